// Round 1
// 249.127 us; speedup vs baseline: 1.5192x; 1.5192x over previous
//
#include <hip/hip_runtime.h>

// MHA forward. L=S=1024, N=4, E=1024, H=16, hd=64, B=N*H=64, M=L*N=4096
// Inputs fp32, outputs fp32 (out0=attn_output 4.19M, out1=attn_weights 4.19M @+4194304).
// Round 7: attn_ctx_mfma was 123 us with MfmaUtil 5.4% / VALUBusy 13.5% / HBM 8%
// -- pure latency-bound: per-wave global K/V fragment loads serialized behind the
// P-roundtrip "memory" clobber. This round: both attention kernels stage K/V tiles
// in LDS (double-buffered, global_load_lds w=16, XOR-swizzled via pre-swizzled
// global source addresses), shared across the 4 waves (4x less L2 traffic).
// P buffer moves to swizzled [16][64] so ctx LDS = 40960 B exactly -> 4 blocks/CU.
// GEMM + convert kernels unchanged. Numerics bit-identical (same bf16 data, same
// MFMA/exp order).
typedef unsigned short u16;
typedef __attribute__((ext_vector_type(8))) short short8;   // 8 bf16 (4 VGPRs)
typedef __attribute__((ext_vector_type(4))) float f32x4;    // MFMA accumulator

__device__ __forceinline__ u16 f2bf(float f) {  // RNE
  unsigned int i = __float_as_uint(f);
  i += 0x7fffu + ((i >> 16) & 1u);
  return (u16)(i >> 16);
}

__device__ __forceinline__ short8 cvt8(const float* p) {
  float4 a = ((const float4*)p)[0];
  float4 b = ((const float4*)p)[1];
  short8 r;
  r[0] = (short)f2bf(a.x); r[1] = (short)f2bf(a.y);
  r[2] = (short)f2bf(a.z); r[3] = (short)f2bf(a.w);
  r[4] = (short)f2bf(b.x); r[5] = (short)f2bf(b.y);
  r[6] = (short)f2bf(b.z); r[7] = (short)f2bf(b.w);
  return r;
}

// ---------------------------------------------------------------------------
// Kernel 0: one-shot fp32 -> bf16 conversion of q/k/v/W_in/W_out. (unchanged)
// ---------------------------------------------------------------------------
__global__ __launch_bounds__(256) void convert_bf16(
    const float* __restrict__ q, const float* __restrict__ k,
    const float* __restrict__ v, const float* __restrict__ Wi,
    const float* __restrict__ Wo,
    u16* __restrict__ qb, u16* __restrict__ kb, u16* __restrict__ vb,
    u16* __restrict__ Wib, u16* __restrict__ Wob)
{
  const float* src; u16* dst; int len8;
  switch (blockIdx.y) {
    case 0:  src = q;  dst = qb;  len8 = 524288; break;  // 4M elts
    case 1:  src = k;  dst = kb;  len8 = 524288; break;
    case 2:  src = v;  dst = vb;  len8 = 524288; break;
    case 3:  src = Wi; dst = Wib; len8 = 393216; break;  // 3M elts
    default: src = Wo; dst = Wob; len8 = 131072; break;  // 1M elts
  }
  int stride = gridDim.x * 256;
  for (int i = blockIdx.x * 256 + threadIdx.x; i < len8; i += stride)
    *(short8*)(dst + (size_t)i * 8) = cvt8(src + (size_t)i * 8);
}

// ---------------------------------------------------------------------------
// Kernel 1: packed QKV projection, 128x128 LDS-tiled. (unchanged)
// ---------------------------------------------------------------------------
__global__ __launch_bounds__(256) void qkv_gemm(
    const u16* __restrict__ qb, const u16* __restrict__ kb,
    const u16* __restrict__ vb, const u16* __restrict__ W,
    const float* __restrict__ bias,
    u16* __restrict__ qh, u16* __restrict__ kh, u16* __restrict__ vt)
{
  __shared__ __align__(16) u16 As[128 * 40];
  __shared__ __align__(16) u16 Bs[128 * 40];

  const int tid  = threadIdx.x;
  const int wave = tid >> 6;
  const int lane = tid & 63;
  const int r    = lane & 15;
  const int q4   = lane >> 4;
  const int wm   = wave >> 1;          // 0..1  (row quadrant)
  const int wn   = wave & 1;           // 0..1  (col quadrant)

  const int jt = blockIdx.x;           // 0..23
  const int mt = blockIdx.y;           // 0..31
  const int src = jt >> 3;             // 0=q, 1=k, 2=v
  const u16* X = (src == 0) ? qb : (src == 1) ? kb : vb;
  const int m0 = mt * 128;
  const int j0 = jt * 128;

  const int trow = tid >> 2;           // 0..63
  const int tcol = (tid & 3) * 8;      // 0,8,16,24

  f32x4 acc[4][4];
  #pragma unroll
  for (int a = 0; a < 4; ++a)
    #pragma unroll
    for (int b = 0; b < 4; ++b)
      acc[a][b] = (f32x4){0.f, 0.f, 0.f, 0.f};

  for (int kk = 0; kk < 1024; kk += 32) {
    short8 a0 = *(const short8*)(X + (size_t)(m0 + trow) * 1024 + kk + tcol);
    short8 a1 = *(const short8*)(X + (size_t)(m0 + 64 + trow) * 1024 + kk + tcol);
    short8 b0 = *(const short8*)(W + (size_t)(j0 + trow) * 1024 + kk + tcol);
    short8 b1 = *(const short8*)(W + (size_t)(j0 + 64 + trow) * 1024 + kk + tcol);
    __syncthreads();
    *(short8*)(As + trow * 40 + tcol) = a0;
    *(short8*)(As + (64 + trow) * 40 + tcol) = a1;
    *(short8*)(Bs + trow * 40 + tcol) = b0;
    *(short8*)(Bs + (64 + trow) * 40 + tcol) = b1;
    __syncthreads();

    const u16* Ab = As + (wm * 64) * 40;
    const u16* Bb = Bs + (wn * 64) * 40;
    short8 af[4], bf[4];
    #pragma unroll
    for (int mi = 0; mi < 4; ++mi)
      af[mi] = *(const short8*)(Ab + (mi * 16 + r) * 40 + q4 * 8);
    #pragma unroll
    for (int ji = 0; ji < 4; ++ji)
      bf[ji] = *(const short8*)(Bb + (ji * 16 + r) * 40 + q4 * 8);
    #pragma unroll
    for (int mi = 0; mi < 4; ++mi)
      #pragma unroll
      for (int ji = 0; ji < 4; ++ji)
        acc[mi][ji] = __builtin_amdgcn_mfma_f32_16x16x32_bf16(af[mi], bf[ji], acc[mi][ji], 0, 0, 0);
  }

  #pragma unroll
  for (int mi = 0; mi < 4; ++mi) {
    #pragma unroll
    for (int ji = 0; ji < 4; ++ji) {
      #pragma unroll
      for (int rr = 0; rr < 4; ++rr) {
        int m = m0 + wm * 64 + mi * 16 + q4 * 4 + rr;  // row = t*4+n
        int j = j0 + wn * 64 + ji * 16 + r;            // col in [0,3072)
        float v = acc[mi][ji][rr] + bias[j];
        int t = m >> 2, n = m & 3;
        int jj = j & 1023;
        int h = jj >> 6, d = jj & 63;
        int bb = n * 16 + h;
        if (src == 0)
          qh[(size_t)bb * 65536 + (size_t)t * 64 + d] = f2bf(v * 0.125f);
        else if (src == 1)
          kh[(size_t)bb * 65536 + (size_t)t * 64 + d] = f2bf(v);
        else
          vt[(size_t)bb * 65536 + (size_t)d * 1024 + t] = f2bf(v);   // transposed
      }
    }
  }
}

// ---------------------------------------------------------------------------
// Kernel 2: attention context, MFMA flash-style. Round-7 rewrite:
// K/V tiles (64x64 bf16 each) staged cooperatively in LDS, double-buffered.
// global_load_lds writes linearly; the XOR swizzle (chunk ^= row&7, 16B chunks)
// is realized by pre-swizzling the per-lane GLOBAL source address (guide m173).
// ds_read_b128 fragment reads use the same swizzle -> 2-way bank alias (free).
// Stage for tile t+1 issued mid-iteration; one __syncthreads per iteration
// provides the vmcnt(0) drain + cross-wave publish. P is per-wave swizzled
// [16][64]. LDS total = 16K(K) + 16K(V) + 8K(P) = 40960 B -> 4 blocks/CU.
// ---------------------------------------------------------------------------
__global__ __launch_bounds__(256) void attn_ctx_mfma(
    const u16* __restrict__ qh, const u16* __restrict__ kh,
    const u16* __restrict__ vt, u16* __restrict__ ctx,
    float* __restrict__ Zbuf)
{
  __shared__ __align__(16) u16 Ks[2][4096];   // 64 rows x 8 chunks x 8 bf16
  __shared__ __align__(16) u16 Vs[2][4096];
  __shared__ __align__(16) u16 Pl[4][1024];   // per-wave P[16][64], swizzled

  const int tid = threadIdx.x;
  const int wv = tid >> 6, lane = tid & 63, r = lane & 15, q4 = lane >> 4;
  const int b  = blockIdx.y;
  const int lw = blockIdx.x * 64 + wv * 16;
  const int n = b >> 4, h = b & 15;

  const u16* qbase = qh + (size_t)b * 65536;
  const char* kc = (const char*)(kh + (size_t)b * 65536);
  const char* vc = (const char*)(vt + (size_t)b * 65536);
  u16* P = Pl[wv];

  // staging geometry: 8 x 1KB global_load_lds per tile, wave wv issues i=2wv,2wv+1
  const int ls  = lane >> 3;               // row-in-octet 0..7
  const int swzb = ((lane & 7) ^ ls) << 4; // swizzled 16B-chunk byte offset
  const int iw  = wv * 2;
  const size_t klo = (size_t)iw * 1024 + (size_t)ls * 128 + swzb;   // K row = 128 B
  const size_t vlo = (size_t)iw * 16384 + (size_t)ls * 2048 + swzb; // V row = 2048 B

  // fragment-read swizzle constants
  const int rsw = r & 7;
  const int c0 = (q4 ^ rsw) << 3;          // u16 offset of logical chunk q4
  const int c1 = ((q4 ^ rsw) ^ 4) << 3;    // logical chunk q4+4

  short8 aq0 = *(const short8*)(qbase + (size_t)(lw + r) * 64 + q4 * 8);
  short8 aq1 = *(const short8*)(qbase + (size_t)(lw + r) * 64 + 32 + q4 * 8);

  f32x4 oc[4];
  #pragma unroll
  for (int ji = 0; ji < 4; ++ji) oc[ji] = (f32x4){0.f, 0.f, 0.f, 0.f};
  float z[4] = {0.f, 0.f, 0.f, 0.f};

  // prologue: stage tile 0 into buffer 0
  {
    const char* kp = kc + klo;
    const char* vp = vc + vlo;
    u16* kd = &Ks[0][iw * 512];
    u16* vd = &Vs[0][iw * 512];
    __builtin_amdgcn_global_load_lds(kp,          kd,       16, 0, 0);
    __builtin_amdgcn_global_load_lds(kp + 1024,   kd + 512, 16, 0, 0);
    __builtin_amdgcn_global_load_lds(vp,          vd,       16, 0, 0);
    __builtin_amdgcn_global_load_lds(vp + 16384,  vd + 512, 16, 0, 0);
  }

  for (int it = 0; it < 16; ++it) {
    const int cur = it & 1;
    __syncthreads();   // drains vmcnt -> Ks/Vs[cur] staged; prev-iter reads done
    const u16* Kb = Ks[cur];
    const u16* Vb = Vs[cur];

    f32x4 sc[4];
    #pragma unroll
    for (int ji = 0; ji < 4; ++ji) {
      const int row = (ji * 16 + r) * 64;
      short8 bk0 = *(const short8*)(Kb + row + c0);
      short8 bk1 = *(const short8*)(Kb + row + c1);
      f32x4 t = (f32x4){0.f, 0.f, 0.f, 0.f};
      t = __builtin_amdgcn_mfma_f32_16x16x32_bf16(aq0, bk0, t, 0, 0, 0);
      t = __builtin_amdgcn_mfma_f32_16x16x32_bf16(aq1, bk1, t, 0, 0, 0);
      sc[ji] = t;
    }

    // stage next tile (lands by next iteration's barrier; latency hides under
    // exp + P-roundtrip + PV below)
    if (it < 15) {
      const char* kp = kc + (size_t)(it + 1) * 8192 + klo;  // 64 rows * 128 B
      const char* vp = vc + (size_t)(it + 1) * 128  + vlo;  // 64 cols * 2 B
      u16* kd = &Ks[cur ^ 1][iw * 512];
      u16* vd = &Vs[cur ^ 1][iw * 512];
      __builtin_amdgcn_global_load_lds(kp,          kd,       16, 0, 0);
      __builtin_amdgcn_global_load_lds(kp + 1024,   kd + 512, 16, 0, 0);
      __builtin_amdgcn_global_load_lds(vp,          vd,       16, 0, 0);
      __builtin_amdgcn_global_load_lds(vp + 16384,  vd + 512, 16, 0, 0);
    }

    #pragma unroll
    for (int ji = 0; ji < 4; ++ji) {
      const int cw = ji * 2 + (r >> 3);   // logical 8-elt chunk of col ji*16+r
      #pragma unroll
      for (int rr = 0; rr < 4; ++rr) {
        float e = __expf(sc[ji][rr]);
        z[rr] += e;
        const int row = q4 * 4 + rr;
        P[row * 64 + ((cw ^ (row & 7)) << 3) + (r & 7)] = f2bf(e);
      }
    }
    asm volatile("s_waitcnt lgkmcnt(0)" ::: "memory");
    short8 ap0 = *(const short8*)(P + r * 64 + c0);
    short8 ap1 = *(const short8*)(P + r * 64 + c1);
    #pragma unroll
    for (int ji = 0; ji < 4; ++ji) {
      const int row = (ji * 16 + r) * 64;
      short8 bv0 = *(const short8*)(Vb + row + c0);
      short8 bv1 = *(const short8*)(Vb + row + c1);
      oc[ji] = __builtin_amdgcn_mfma_f32_16x16x32_bf16(ap0, bv0, oc[ji], 0, 0, 0);
      oc[ji] = __builtin_amdgcn_mfma_f32_16x16x32_bf16(ap1, bv1, oc[ji], 0, 0, 0);
    }
  }

  #pragma unroll
  for (int rr = 0; rr < 4; ++rr) {
    float zz = z[rr];
    zz += __shfl_xor(zz, 1);
    zz += __shfl_xor(zz, 2);
    zz += __shfl_xor(zz, 4);
    zz += __shfl_xor(zz, 8);
    z[rr] = zz;
  }

  #pragma unroll
  for (int rr = 0; rr < 4; ++rr) {
    float inv = 1.0f / z[rr];
    int l = lw + q4 * 4 + rr;
    u16* crow = ctx + ((size_t)l * 4 + n) * 1024 + h * 64;
    #pragma unroll
    for (int ji = 0; ji < 4; ++ji)
      crow[ji * 16 + r] = f2bf(oc[ji][rr] * inv);
    if (r == 0) Zbuf[(size_t)b * 1024 + l] = z[rr];
  }
}

// ---------------------------------------------------------------------------
// Kernel 3: head-averaged attention weights. Round-7 rewrite: K tile for head
// hh staged in LDS (double-buffered across heads, same XOR swizzle as ctx),
// next head's Q fragments prefetched into registers.
// ---------------------------------------------------------------------------
__global__ __launch_bounds__(256) void attn_w_mfma(
    const u16* __restrict__ qh, const u16* __restrict__ kh,
    const float* __restrict__ Zbuf, float* __restrict__ out_w)
{
  __shared__ __align__(16) u16 Kw[2][4096];
  __shared__ float invZ[16][64];

  const int tid = threadIdx.x;
  const int wv = tid >> 6, lane = tid & 63, r = lane & 15, q4 = lane >> 4;
  const int lt = blockIdx.x;
  const int st = blockIdx.y;
  const int n  = blockIdx.z;
  const int l0 = lt * 64;
  const int s0 = st * 64;
  const int lw = l0 + wv * 16;

  const char* khc = (const char*)kh + (size_t)n * 2097152;  // 16 heads * 128 KB

  const int ls  = lane >> 3;
  const int swzb = ((lane & 7) ^ ls) << 4;
  const int iw  = wv * 2;
  const size_t klo = (size_t)s0 * 128 + (size_t)iw * 1024 + (size_t)ls * 128 + swzb;

  const int rsw = r & 7;
  const int c0 = (q4 ^ rsw) << 3;
  const int c1 = ((q4 ^ rsw) ^ 4) << 3;

  for (int i = tid; i < 1024; i += 256) {
    int hh = i >> 6, row = i & 63;
    invZ[hh][row] = 1.0f / (Zbuf[(size_t)(n * 16 + hh) * 1024 + l0 + row] * 16.0f);
  }

  // prologue: stage head 0 K tile into buffer 0; load head 0 Q fragments
  {
    const char* kp = khc + klo;
    u16* kd = &Kw[0][iw * 512];
    __builtin_amdgcn_global_load_lds(kp,        kd,       16, 0, 0);
    __builtin_amdgcn_global_load_lds(kp + 1024, kd + 512, 16, 0, 0);
  }
  const u16* q0 = qh + (size_t)(n * 16) * 65536;
  short8 aqc0 = *(const short8*)(q0 + (size_t)(lw + r) * 64 + q4 * 8);
  short8 aqc1 = *(const short8*)(q0 + (size_t)(lw + r) * 64 + 32 + q4 * 8);

  f32x4 wacc[4];
  #pragma unroll
  for (int ji = 0; ji < 4; ++ji) wacc[ji] = (f32x4){0.f, 0.f, 0.f, 0.f};

  for (int hh = 0; hh < 16; ++hh) {
    const int cur = hh & 1;
    __syncthreads();   // Kw[cur] staged (and invZ on first iter); prev reads done
    if (hh < 15) {
      const char* kp = khc + (size_t)(hh + 1) * 131072 + klo;
      u16* kd = &Kw[cur ^ 1][iw * 512];
      __builtin_amdgcn_global_load_lds(kp,        kd,       16, 0, 0);
      __builtin_amdgcn_global_load_lds(kp + 1024, kd + 512, 16, 0, 0);
    }
    // prefetch next head's Q fragments (overlaps exp below)
    const int hn = (hh < 15) ? hh + 1 : hh;
    const u16* qn = qh + (size_t)(n * 16 + hn) * 65536;
    short8 an0 = *(const short8*)(qn + (size_t)(lw + r) * 64 + q4 * 8);
    short8 an1 = *(const short8*)(qn + (size_t)(lw + r) * 64 + 32 + q4 * 8);

    const u16* Kb = Kw[cur];
    f32x4 sc[4];
    #pragma unroll
    for (int ji = 0; ji < 4; ++ji) {
      const int row = (ji * 16 + r) * 64;
      short8 bk0 = *(const short8*)(Kb + row + c0);
      short8 bk1 = *(const short8*)(Kb + row + c1);
      f32x4 t = (f32x4){0.f, 0.f, 0.f, 0.f};
      t = __builtin_amdgcn_mfma_f32_16x16x32_bf16(aqc0, bk0, t, 0, 0, 0);
      t = __builtin_amdgcn_mfma_f32_16x16x32_bf16(aqc1, bk1, t, 0, 0, 0);
      sc[ji] = t;
    }
    #pragma unroll
    for (int rr = 0; rr < 4; ++rr) {
      float iv = invZ[hh][wv * 16 + q4 * 4 + rr];
      #pragma unroll
      for (int ji = 0; ji < 4; ++ji)
        wacc[ji][rr] += __expf(sc[ji][rr]) * iv;
    }
    aqc0 = an0; aqc1 = an1;
  }

  #pragma unroll
  for (int ji = 0; ji < 4; ++ji)
    #pragma unroll
    for (int rr = 0; rr < 4; ++rr) {
      int row = lw + q4 * 4 + rr;
      int col = s0 + ji * 16 + r;
      out_w[(size_t)n * 1048576 + (size_t)row * 1024 + col] = wacc[ji][rr];
    }
}

// ---------------------------------------------------------------------------
// Kernel 4: output projection, 128x128 LDS-tiled. (unchanged)
// ---------------------------------------------------------------------------
__global__ __launch_bounds__(256) void out_gemm(
    const u16* __restrict__ ctx, const u16* __restrict__ W,
    const float* __restrict__ bias, float* __restrict__ out)
{
  __shared__ __align__(16) u16 As[128 * 40];
  __shared__ __align__(16) u16 Bs[128 * 40];

  const int tid  = threadIdx.x;
  const int wave = tid >> 6;
  const int lane = tid & 63;
  const int r    = lane & 15;
  const int q4   = lane >> 4;
  const int wm   = wave >> 1;
  const int wn   = wave & 1;

  const int j0 = blockIdx.x * 128;     // 0..7 tiles
  const int m0 = blockIdx.y * 128;     // 0..31 tiles

  const int trow = tid >> 2;
  const int tcol = (tid & 3) * 8;

  f32x4 acc[4][4];
  #pragma unroll
  for (int a = 0; a < 4; ++a)
    #pragma unroll
    for (int b = 0; b < 4; ++b)
      acc[a][b] = (f32x4){0.f, 0.f, 0.f, 0.f};

  for (int kk = 0; kk < 1024; kk += 32) {
    short8 a0 = *(const short8*)(ctx + (size_t)(m0 + trow) * 1024 + kk + tcol);
    short8 a1 = *(const short8*)(ctx + (size_t)(m0 + 64 + trow) * 1024 + kk + tcol);
    short8 b0 = *(const short8*)(W + (size_t)(j0 + trow) * 1024 + kk + tcol);
    short8 b1 = *(const short8*)(W + (size_t)(j0 + 64 + trow) * 1024 + kk + tcol);
    __syncthreads();
    *(short8*)(As + trow * 40 + tcol) = a0;
    *(short8*)(As + (64 + trow) * 40 + tcol) = a1;
    *(short8*)(Bs + trow * 40 + tcol) = b0;
    *(short8*)(Bs + (64 + trow) * 40 + tcol) = b1;
    __syncthreads();

    const u16* Ab = As + (wm * 64) * 40;
    const u16* Bb = Bs + (wn * 64) * 40;
    short8 af[4], bf[4];
    #pragma unroll
    for (int mi = 0; mi < 4; ++mi)
      af[mi] = *(const short8*)(Ab + (mi * 16 + r) * 40 + q4 * 8);
    #pragma unroll
    for (int ji = 0; ji < 4; ++ji)
      bf[ji] = *(const short8*)(Bb + (ji * 16 + r) * 40 + q4 * 8);
    #pragma unroll
    for (int mi = 0; mi < 4; ++mi)
      #pragma unroll
      for (int ji = 0; ji < 4; ++ji)
        acc[mi][ji] = __builtin_amdgcn_mfma_f32_16x16x32_bf16(af[mi], bf[ji], acc[mi][ji], 0, 0, 0);
  }

  #pragma unroll
  for (int mi = 0; mi < 4; ++mi) {
    #pragma unroll
    for (int ji = 0; ji < 4; ++ji) {
      #pragma unroll
      for (int rr = 0; rr < 4; ++rr) {
        int m = m0 + wm * 64 + mi * 16 + q4 * 4 + rr;
        int j = j0 + wn * 64 + ji * 16 + r;
        out[(size_t)m * 1024 + j] = acc[mi][ji][rr] + bias[j];
      }
    }
  }
}

// ---------------------------------------------------------------------------
extern "C" void kernel_launch(void* const* d_in, const int* in_sizes, int n_in,
                              void* d_out, int out_size, void* d_ws, size_t ws_size,
                              hipStream_t stream) {
  const float* query = (const float*)d_in[0];
  const float* key   = (const float*)d_in[1];
  const float* value = (const float*)d_in[2];
  const float* W_in  = (const float*)d_in[3];
  const float* b_in  = (const float*)d_in[4];
  const float* W_out = (const float*)d_in[5];
  const float* b_out = (const float*)d_in[6];
  float* out = (float*)d_out;

  // ws (~64.3 MB): qb 8 | kb 8 | vb 8 | Wib 6 | Wob 2 | qh 8 | kh 8 | vt 8 | ctx 8 | Z .25
  u16* qb  = (u16*)d_ws;
  u16* kb  = qb  + (size_t)4194304;
  u16* vb  = kb  + (size_t)4194304;
  u16* Wib = vb  + (size_t)4194304;
  u16* Wob = Wib + (size_t)3145728;
  u16* qh  = Wob + (size_t)1048576;
  u16* kh  = qh  + (size_t)4194304;
  u16* vt  = kh  + (size_t)4194304;
  u16* ctx = vt  + (size_t)4194304;
  float* Zbuf = (float*)(ctx + (size_t)4194304);

  convert_bf16<<<dim3(512, 5), 256, 0, stream>>>(query, key, value, W_in, W_out,
                                                 qb, kb, vb, Wib, Wob);
  qkv_gemm<<<dim3(24, 32), 256, 0, stream>>>(qb, kb, vb, Wib, b_in, qh, kh, vt);
  attn_ctx_mfma<<<dim3(16, 64), 256, 0, stream>>>(qh, kh, vt, ctx, Zbuf);
  attn_w_mfma<<<dim3(16, 16, 4), 256, 0, stream>>>(qh, kh, Zbuf, out + (size_t)4194304);
  out_gemm<<<dim3(8, 32), 256, 0, stream>>>(ctx, Wob, b_out, out);
}

// Round 2
// 246.105 us; speedup vs baseline: 1.5379x; 1.0123x over previous
//
#include <hip/hip_runtime.h>

// MHA forward. L=S=1024, N=4, E=1024, H=16, hd=64, B=N*H=64, M=L*N=4096
// Inputs fp32, outputs fp32 (out0=attn_output 4.19M, out1=attn_weights 4.19M @+4194304).
// Round 8: qkv_gemm was 54.6 us, MfmaUtil 18%, BANK_CONFLICT 6.3M -- reg-staged
// LDS with 80B-padded rows. This round both GEMMs move to the m97/m151 pattern:
// BK=64, linear LDS tiles with XOR chunk swizzle (chunk ^= row&7, 128B rows),
// staged via global_load_lds w=16 with pre-swizzled per-lane GLOBAL addresses
// (LDS dest stays linear: wave-uniform base + lane*16). Plus XCD-chunked block
// swizzle so same-A-slab blocks share one XCD's L2. Attention kernels unchanged.
typedef unsigned short u16;
typedef __attribute__((ext_vector_type(8))) short short8;   // 8 bf16 (4 VGPRs)
typedef __attribute__((ext_vector_type(4))) float f32x4;    // MFMA accumulator

__device__ __forceinline__ u16 f2bf(float f) {  // RNE
  unsigned int i = __float_as_uint(f);
  i += 0x7fffu + ((i >> 16) & 1u);
  return (u16)(i >> 16);
}

__device__ __forceinline__ short8 cvt8(const float* p) {
  float4 a = ((const float4*)p)[0];
  float4 b = ((const float4*)p)[1];
  short8 r;
  r[0] = (short)f2bf(a.x); r[1] = (short)f2bf(a.y);
  r[2] = (short)f2bf(a.z); r[3] = (short)f2bf(a.w);
  r[4] = (short)f2bf(b.x); r[5] = (short)f2bf(b.y);
  r[6] = (short)f2bf(b.z); r[7] = (short)f2bf(b.w);
  return r;
}

// ---------------------------------------------------------------------------
// Kernel 0: one-shot fp32 -> bf16 conversion of q/k/v/W_in/W_out. (unchanged)
// ---------------------------------------------------------------------------
__global__ __launch_bounds__(256) void convert_bf16(
    const float* __restrict__ q, const float* __restrict__ k,
    const float* __restrict__ v, const float* __restrict__ Wi,
    const float* __restrict__ Wo,
    u16* __restrict__ qb, u16* __restrict__ kb, u16* __restrict__ vb,
    u16* __restrict__ Wib, u16* __restrict__ Wob)
{
  const float* src; u16* dst; int len8;
  switch (blockIdx.y) {
    case 0:  src = q;  dst = qb;  len8 = 524288; break;  // 4M elts
    case 1:  src = k;  dst = kb;  len8 = 524288; break;
    case 2:  src = v;  dst = vb;  len8 = 524288; break;
    case 3:  src = Wi; dst = Wib; len8 = 393216; break;  // 3M elts
    default: src = Wo; dst = Wob; len8 = 131072; break;  // 1M elts
  }
  int stride = gridDim.x * 256;
  for (int i = blockIdx.x * 256 + threadIdx.x; i < len8; i += stride)
    *(short8*)(dst + (size_t)i * 8) = cvt8(src + (size_t)i * 8);
}

// ---------------------------------------------------------------------------
// Kernel 1: packed QKV projection. Round-8 rewrite: 128x128 tile, BK=64,
// global_load_lds w=16 into linear XOR-swizzled LDS (row=128B, chunk^=row&7),
// XCD-chunked block swizzle (768 blocks -> 96/XCD, consecutive share A-slab).
// C[m][j] = X[m][:].W[j][:] + bias[j]; M=4096, K=1024, J=3072 (bf16 inputs).
// ---------------------------------------------------------------------------
__global__ __launch_bounds__(256) void qkv_gemm(
    const u16* __restrict__ qb, const u16* __restrict__ kb,
    const u16* __restrict__ vb, const u16* __restrict__ W,
    const float* __restrict__ bias,
    u16* __restrict__ qh, u16* __restrict__ kh, u16* __restrict__ vt)
{
  __shared__ __align__(16) u16 As[128 * 64];   // 16 KB, swizzled
  __shared__ __align__(16) u16 Bs[128 * 64];   // 16 KB, swizzled

  const int tid  = threadIdx.x;
  const int wave = tid >> 6;
  const int lane = tid & 63;
  const int r    = lane & 15;
  const int q4   = lane >> 4;
  const int wm   = wave >> 1;          // 0..1  (row quadrant)
  const int wn   = wave & 1;           // 0..1  (col quadrant)

  // XCD-chunked swizzle: hw id h -> xcd h&7; logical nid = (h&7)*96 + h>>3.
  // Logical order nid = mt*24 + jt => one XCD covers 4 m-tiles x all j-tiles
  // (A-slabs L2-resident per XCD; W rides L3).
  const int orig = blockIdx.y * 24 + blockIdx.x;
  const int nid  = (orig & 7) * 96 + (orig >> 3);
  const int mt   = nid / 24;           // 0..31
  const int jt   = nid - mt * 24;      // 0..23
  const int src  = jt >> 3;            // 0=q, 1=k, 2=v
  const u16* X = (src == 0) ? qb : (src == 1) ? kb : vb;
  const int m0 = mt * 128;
  const int j0 = jt * 128;

  // staging geometry: per load i (0..3), wave w covers rows w*32+i*8+ls
  const int ls   = lane >> 3;              // row-in-octet 0..7
  const int swzb = ((lane & 7) ^ ls) << 4; // pre-swizzled 16B-chunk byte offset
  const char* Xc = (const char*)X;
  const char* Wc = (const char*)W;

  f32x4 acc[4][4];
  #pragma unroll
  for (int a = 0; a < 4; ++a)
    #pragma unroll
    for (int b = 0; b < 4; ++b)
      acc[a][b] = (f32x4){0.f, 0.f, 0.f, 0.f};

  for (int kt = 0; kt < 16; ++kt) {
    const int kb2 = kt * 128;            // byte offset within a 2048B row
    __syncthreads();                     // all waves done reading prev tile
    #pragma unroll
    for (int i = 0; i < 4; ++i) {
      const int row = wave * 32 + i * 8 + ls;
      __builtin_amdgcn_global_load_lds(
          (const u16*)(Xc + (size_t)(m0 + row) * 2048 + kb2 + swzb),
          As + (wave * 4 + i) * 512, 16, 0, 0);
      __builtin_amdgcn_global_load_lds(
          (const u16*)(Wc + (size_t)(j0 + row) * 2048 + kb2 + swzb),
          Bs + (wave * 4 + i) * 512, 16, 0, 0);
    }
    __syncthreads();                     // staging drained (vmcnt via barrier)

    #pragma unroll
    for (int ks = 0; ks < 2; ++ks) {
      short8 af[4], bf[4];
      #pragma unroll
      for (int mi = 0; mi < 4; ++mi) {
        const int row = wm * 64 + mi * 16 + r;
        af[mi] = *(const short8*)(As + row * 64 + ((((ks << 2) | q4) ^ (r & 7)) << 3));
      }
      #pragma unroll
      for (int ji = 0; ji < 4; ++ji) {
        const int row = wn * 64 + ji * 16 + r;
        bf[ji] = *(const short8*)(Bs + row * 64 + ((((ks << 2) | q4) ^ (r & 7)) << 3));
      }
      #pragma unroll
      for (int mi = 0; mi < 4; ++mi)
        #pragma unroll
        for (int ji = 0; ji < 4; ++ji)
          acc[mi][ji] = __builtin_amdgcn_mfma_f32_16x16x32_bf16(af[mi], bf[ji], acc[mi][ji], 0, 0, 0);
    }
  }

  #pragma unroll
  for (int mi = 0; mi < 4; ++mi) {
    #pragma unroll
    for (int ji = 0; ji < 4; ++ji) {
      #pragma unroll
      for (int rr = 0; rr < 4; ++rr) {
        int m = m0 + wm * 64 + mi * 16 + q4 * 4 + rr;  // row = t*4+n
        int j = j0 + wn * 64 + ji * 16 + r;            // col in [0,3072)
        float v = acc[mi][ji][rr] + bias[j];
        int t = m >> 2, n = m & 3;
        int jj = j & 1023;
        int h = jj >> 6, d = jj & 63;
        int bb = n * 16 + h;
        if (src == 0)
          qh[(size_t)bb * 65536 + (size_t)t * 64 + d] = f2bf(v * 0.125f);
        else if (src == 1)
          kh[(size_t)bb * 65536 + (size_t)t * 64 + d] = f2bf(v);
        else
          vt[(size_t)bb * 65536 + (size_t)d * 1024 + t] = f2bf(v);   // transposed
      }
    }
  }
}

// ---------------------------------------------------------------------------
// Kernel 2: attention context, MFMA flash-style. (unchanged from round 7)
// ---------------------------------------------------------------------------
__global__ __launch_bounds__(256) void attn_ctx_mfma(
    const u16* __restrict__ qh, const u16* __restrict__ kh,
    const u16* __restrict__ vt, u16* __restrict__ ctx,
    float* __restrict__ Zbuf)
{
  __shared__ __align__(16) u16 Ks[2][4096];   // 64 rows x 8 chunks x 8 bf16
  __shared__ __align__(16) u16 Vs[2][4096];
  __shared__ __align__(16) u16 Pl[4][1024];   // per-wave P[16][64], swizzled

  const int tid = threadIdx.x;
  const int wv = tid >> 6, lane = tid & 63, r = lane & 15, q4 = lane >> 4;
  const int b  = blockIdx.y;
  const int lw = blockIdx.x * 64 + wv * 16;
  const int n = b >> 4, h = b & 15;

  const u16* qbase = qh + (size_t)b * 65536;
  const char* kc = (const char*)(kh + (size_t)b * 65536);
  const char* vc = (const char*)(vt + (size_t)b * 65536);
  u16* P = Pl[wv];

  const int ls  = lane >> 3;               // row-in-octet 0..7
  const int swzb = ((lane & 7) ^ ls) << 4; // swizzled 16B-chunk byte offset
  const int iw  = wv * 2;
  const size_t klo = (size_t)iw * 1024 + (size_t)ls * 128 + swzb;   // K row = 128 B
  const size_t vlo = (size_t)iw * 16384 + (size_t)ls * 2048 + swzb; // V row = 2048 B

  const int rsw = r & 7;
  const int c0 = (q4 ^ rsw) << 3;          // u16 offset of logical chunk q4
  const int c1 = ((q4 ^ rsw) ^ 4) << 3;    // logical chunk q4+4

  short8 aq0 = *(const short8*)(qbase + (size_t)(lw + r) * 64 + q4 * 8);
  short8 aq1 = *(const short8*)(qbase + (size_t)(lw + r) * 64 + 32 + q4 * 8);

  f32x4 oc[4];
  #pragma unroll
  for (int ji = 0; ji < 4; ++ji) oc[ji] = (f32x4){0.f, 0.f, 0.f, 0.f};
  float z[4] = {0.f, 0.f, 0.f, 0.f};

  {
    const char* kp = kc + klo;
    const char* vp = vc + vlo;
    u16* kd = &Ks[0][iw * 512];
    u16* vd = &Vs[0][iw * 512];
    __builtin_amdgcn_global_load_lds(kp,          kd,       16, 0, 0);
    __builtin_amdgcn_global_load_lds(kp + 1024,   kd + 512, 16, 0, 0);
    __builtin_amdgcn_global_load_lds(vp,          vd,       16, 0, 0);
    __builtin_amdgcn_global_load_lds(vp + 16384,  vd + 512, 16, 0, 0);
  }

  for (int it = 0; it < 16; ++it) {
    const int cur = it & 1;
    __syncthreads();   // drains vmcnt -> Ks/Vs[cur] staged; prev-iter reads done
    const u16* Kb = Ks[cur];
    const u16* Vb = Vs[cur];

    f32x4 sc[4];
    #pragma unroll
    for (int ji = 0; ji < 4; ++ji) {
      const int row = (ji * 16 + r) * 64;
      short8 bk0 = *(const short8*)(Kb + row + c0);
      short8 bk1 = *(const short8*)(Kb + row + c1);
      f32x4 t = (f32x4){0.f, 0.f, 0.f, 0.f};
      t = __builtin_amdgcn_mfma_f32_16x16x32_bf16(aq0, bk0, t, 0, 0, 0);
      t = __builtin_amdgcn_mfma_f32_16x16x32_bf16(aq1, bk1, t, 0, 0, 0);
      sc[ji] = t;
    }

    if (it < 15) {
      const char* kp = kc + (size_t)(it + 1) * 8192 + klo;  // 64 rows * 128 B
      const char* vp = vc + (size_t)(it + 1) * 128  + vlo;  // 64 cols * 2 B
      u16* kd = &Ks[cur ^ 1][iw * 512];
      u16* vd = &Vs[cur ^ 1][iw * 512];
      __builtin_amdgcn_global_load_lds(kp,          kd,       16, 0, 0);
      __builtin_amdgcn_global_load_lds(kp + 1024,   kd + 512, 16, 0, 0);
      __builtin_amdgcn_global_load_lds(vp,          vd,       16, 0, 0);
      __builtin_amdgcn_global_load_lds(vp + 16384,  vd + 512, 16, 0, 0);
    }

    #pragma unroll
    for (int ji = 0; ji < 4; ++ji) {
      const int cw = ji * 2 + (r >> 3);   // logical 8-elt chunk of col ji*16+r
      #pragma unroll
      for (int rr = 0; rr < 4; ++rr) {
        float e = __expf(sc[ji][rr]);
        z[rr] += e;
        const int row = q4 * 4 + rr;
        P[row * 64 + ((cw ^ (row & 7)) << 3) + (r & 7)] = f2bf(e);
      }
    }
    asm volatile("s_waitcnt lgkmcnt(0)" ::: "memory");
    short8 ap0 = *(const short8*)(P + r * 64 + c0);
    short8 ap1 = *(const short8*)(P + r * 64 + c1);
    #pragma unroll
    for (int ji = 0; ji < 4; ++ji) {
      const int row = (ji * 16 + r) * 64;
      short8 bv0 = *(const short8*)(Vb + row + c0);
      short8 bv1 = *(const short8*)(Vb + row + c1);
      oc[ji] = __builtin_amdgcn_mfma_f32_16x16x32_bf16(ap0, bv0, oc[ji], 0, 0, 0);
      oc[ji] = __builtin_amdgcn_mfma_f32_16x16x32_bf16(ap1, bv1, oc[ji], 0, 0, 0);
    }
  }

  #pragma unroll
  for (int rr = 0; rr < 4; ++rr) {
    float zz = z[rr];
    zz += __shfl_xor(zz, 1);
    zz += __shfl_xor(zz, 2);
    zz += __shfl_xor(zz, 4);
    zz += __shfl_xor(zz, 8);
    z[rr] = zz;
  }

  #pragma unroll
  for (int rr = 0; rr < 4; ++rr) {
    float inv = 1.0f / z[rr];
    int l = lw + q4 * 4 + rr;
    u16* crow = ctx + ((size_t)l * 4 + n) * 1024 + h * 64;
    #pragma unroll
    for (int ji = 0; ji < 4; ++ji)
      crow[ji * 16 + r] = f2bf(oc[ji][rr] * inv);
    if (r == 0) Zbuf[(size_t)b * 1024 + l] = z[rr];
  }
}

// ---------------------------------------------------------------------------
// Kernel 3: head-averaged attention weights. (unchanged from round 7)
// ---------------------------------------------------------------------------
__global__ __launch_bounds__(256) void attn_w_mfma(
    const u16* __restrict__ qh, const u16* __restrict__ kh,
    const float* __restrict__ Zbuf, float* __restrict__ out_w)
{
  __shared__ __align__(16) u16 Kw[2][4096];
  __shared__ float invZ[16][64];

  const int tid = threadIdx.x;
  const int wv = tid >> 6, lane = tid & 63, r = lane & 15, q4 = lane >> 4;
  const int lt = blockIdx.x;
  const int st = blockIdx.y;
  const int n  = blockIdx.z;
  const int l0 = lt * 64;
  const int s0 = st * 64;
  const int lw = l0 + wv * 16;

  const char* khc = (const char*)kh + (size_t)n * 2097152;  // 16 heads * 128 KB

  const int ls  = lane >> 3;
  const int swzb = ((lane & 7) ^ ls) << 4;
  const int iw  = wv * 2;
  const size_t klo = (size_t)s0 * 128 + (size_t)iw * 1024 + (size_t)ls * 128 + swzb;

  const int rsw = r & 7;
  const int c0 = (q4 ^ rsw) << 3;
  const int c1 = ((q4 ^ rsw) ^ 4) << 3;

  for (int i = tid; i < 1024; i += 256) {
    int hh = i >> 6, row = i & 63;
    invZ[hh][row] = 1.0f / (Zbuf[(size_t)(n * 16 + hh) * 1024 + l0 + row] * 16.0f);
  }

  {
    const char* kp = khc + klo;
    u16* kd = &Kw[0][iw * 512];
    __builtin_amdgcn_global_load_lds(kp,        kd,       16, 0, 0);
    __builtin_amdgcn_global_load_lds(kp + 1024, kd + 512, 16, 0, 0);
  }
  const u16* q0 = qh + (size_t)(n * 16) * 65536;
  short8 aqc0 = *(const short8*)(q0 + (size_t)(lw + r) * 64 + q4 * 8);
  short8 aqc1 = *(const short8*)(q0 + (size_t)(lw + r) * 64 + 32 + q4 * 8);

  f32x4 wacc[4];
  #pragma unroll
  for (int ji = 0; ji < 4; ++ji) wacc[ji] = (f32x4){0.f, 0.f, 0.f, 0.f};

  for (int hh = 0; hh < 16; ++hh) {
    const int cur = hh & 1;
    __syncthreads();   // Kw[cur] staged (and invZ on first iter); prev reads done
    if (hh < 15) {
      const char* kp = khc + (size_t)(hh + 1) * 131072 + klo;
      u16* kd = &Kw[cur ^ 1][iw * 512];
      __builtin_amdgcn_global_load_lds(kp,        kd,       16, 0, 0);
      __builtin_amdgcn_global_load_lds(kp + 1024, kd + 512, 16, 0, 0);
    }
    const int hn = (hh < 15) ? hh + 1 : hh;
    const u16* qn = qh + (size_t)(n * 16 + hn) * 65536;
    short8 an0 = *(const short8*)(qn + (size_t)(lw + r) * 64 + q4 * 8);
    short8 an1 = *(const short8*)(qn + (size_t)(lw + r) * 64 + 32 + q4 * 8);

    const u16* Kb = Kw[cur];
    f32x4 sc[4];
    #pragma unroll
    for (int ji = 0; ji < 4; ++ji) {
      const int row = (ji * 16 + r) * 64;
      short8 bk0 = *(const short8*)(Kb + row + c0);
      short8 bk1 = *(const short8*)(Kb + row + c1);
      f32x4 t = (f32x4){0.f, 0.f, 0.f, 0.f};
      t = __builtin_amdgcn_mfma_f32_16x16x32_bf16(aqc0, bk0, t, 0, 0, 0);
      t = __builtin_amdgcn_mfma_f32_16x16x32_bf16(aqc1, bk1, t, 0, 0, 0);
      sc[ji] = t;
    }
    #pragma unroll
    for (int rr = 0; rr < 4; ++rr) {
      float iv = invZ[hh][wv * 16 + q4 * 4 + rr];
      #pragma unroll
      for (int ji = 0; ji < 4; ++ji)
        wacc[ji][rr] += __expf(sc[ji][rr]) * iv;
    }
    aqc0 = an0; aqc1 = an1;
  }

  #pragma unroll
  for (int ji = 0; ji < 4; ++ji)
    #pragma unroll
    for (int rr = 0; rr < 4; ++rr) {
      int row = lw + q4 * 4 + rr;
      int col = s0 + ji * 16 + r;
      out_w[(size_t)n * 1048576 + (size_t)row * 1024 + col] = wacc[ji][rr];
    }
}

// ---------------------------------------------------------------------------
// Kernel 4: output projection. Round-8 rewrite: 128(M)x64(J) tile, BK=64,
// global_load_lds + XOR swizzle (same pattern as qkv_gemm), grid 512 blocks
// (2/CU). ctx/Wob bf16 in, fp32 out. M=4096, K=1024, J=1024.
// ---------------------------------------------------------------------------
__global__ __launch_bounds__(256) void out_gemm(
    const u16* __restrict__ ctx, const u16* __restrict__ W,
    const float* __restrict__ bias, float* __restrict__ out)
{
  __shared__ __align__(16) u16 As[128 * 64];   // 16 KB, swizzled
  __shared__ __align__(16) u16 Bs[64 * 64];    // 8 KB, swizzled

  const int tid  = threadIdx.x;
  const int wave = tid >> 6;
  const int lane = tid & 63;
  const int r    = lane & 15;
  const int q4   = lane >> 4;
  const int wm   = wave >> 1;          // 0..1 (row half: 64 rows)
  const int wn   = wave & 1;           // 0..1 (col half: 32 cols)

  // XCD-chunked swizzle: 512 blocks -> 64/XCD; logical nid = mt*16 + jt
  const int orig = blockIdx.y * 16 + blockIdx.x;
  const int nid  = (orig & 7) * 64 + (orig >> 3);
  const int mt   = nid >> 4;           // 0..31
  const int jt   = nid & 15;           // 0..15
  const int m0 = mt * 128;
  const int j0 = jt * 64;

  const int ls   = lane >> 3;
  const int swzb = ((lane & 7) ^ ls) << 4;
  const char* Ac = (const char*)ctx;
  const char* Wc = (const char*)W;

  f32x4 acc[4][2];
  #pragma unroll
  for (int a = 0; a < 4; ++a)
    #pragma unroll
    for (int b = 0; b < 2; ++b)
      acc[a][b] = (f32x4){0.f, 0.f, 0.f, 0.f};

  for (int kt = 0; kt < 16; ++kt) {
    const int kb2 = kt * 128;
    __syncthreads();
    #pragma unroll
    for (int i = 0; i < 4; ++i) {
      const int row = wave * 32 + i * 8 + ls;
      __builtin_amdgcn_global_load_lds(
          (const u16*)(Ac + (size_t)(m0 + row) * 2048 + kb2 + swzb),
          As + (wave * 4 + i) * 512, 16, 0, 0);
    }
    #pragma unroll
    for (int i = 0; i < 2; ++i) {
      const int row = wave * 16 + i * 8 + ls;
      __builtin_amdgcn_global_load_lds(
          (const u16*)(Wc + (size_t)(j0 + row) * 2048 + kb2 + swzb),
          Bs + (wave * 2 + i) * 512, 16, 0, 0);
    }
    __syncthreads();

    #pragma unroll
    for (int ks = 0; ks < 2; ++ks) {
      short8 af[4], bf[2];
      #pragma unroll
      for (int mi = 0; mi < 4; ++mi) {
        const int row = wm * 64 + mi * 16 + r;
        af[mi] = *(const short8*)(As + row * 64 + ((((ks << 2) | q4) ^ (r & 7)) << 3));
      }
      #pragma unroll
      for (int ji = 0; ji < 2; ++ji) {
        const int row = wn * 32 + ji * 16 + r;
        bf[ji] = *(const short8*)(Bs + row * 64 + ((((ks << 2) | q4) ^ (r & 7)) << 3));
      }
      #pragma unroll
      for (int mi = 0; mi < 4; ++mi)
        #pragma unroll
        for (int ji = 0; ji < 2; ++ji)
          acc[mi][ji] = __builtin_amdgcn_mfma_f32_16x16x32_bf16(af[mi], bf[ji], acc[mi][ji], 0, 0, 0);
    }
  }

  #pragma unroll
  for (int mi = 0; mi < 4; ++mi) {
    #pragma unroll
    for (int ji = 0; ji < 2; ++ji) {
      #pragma unroll
      for (int rr = 0; rr < 4; ++rr) {
        int m = m0 + wm * 64 + mi * 16 + q4 * 4 + rr;
        int j = j0 + wn * 32 + ji * 16 + r;
        out[(size_t)m * 1024 + j] = acc[mi][ji][rr] + bias[j];
      }
    }
  }
}

// ---------------------------------------------------------------------------
extern "C" void kernel_launch(void* const* d_in, const int* in_sizes, int n_in,
                              void* d_out, int out_size, void* d_ws, size_t ws_size,
                              hipStream_t stream) {
  const float* query = (const float*)d_in[0];
  const float* key   = (const float*)d_in[1];
  const float* value = (const float*)d_in[2];
  const float* W_in  = (const float*)d_in[3];
  const float* b_in  = (const float*)d_in[4];
  const float* W_out = (const float*)d_in[5];
  const float* b_out = (const float*)d_in[6];
  float* out = (float*)d_out;

  // ws (~64.3 MB): qb 8 | kb 8 | vb 8 | Wib 6 | Wob 2 | qh 8 | kh 8 | vt 8 | ctx 8 | Z .25
  u16* qb  = (u16*)d_ws;
  u16* kb  = qb  + (size_t)4194304;
  u16* vb  = kb  + (size_t)4194304;
  u16* Wib = vb  + (size_t)4194304;
  u16* Wob = Wib + (size_t)3145728;
  u16* qh  = Wob + (size_t)1048576;
  u16* kh  = qh  + (size_t)4194304;
  u16* vt  = kh  + (size_t)4194304;
  u16* ctx = vt  + (size_t)4194304;
  float* Zbuf = (float*)(ctx + (size_t)4194304);

  convert_bf16<<<dim3(512, 5), 256, 0, stream>>>(query, key, value, W_in, W_out,
                                                 qb, kb, vb, Wib, Wob);
  qkv_gemm<<<dim3(24, 32), 256, 0, stream>>>(qb, kb, vb, Wib, b_in, qh, kh, vt);
  attn_ctx_mfma<<<dim3(16, 64), 256, 0, stream>>>(qh, kh, vt, ctx, Zbuf);
  attn_w_mfma<<<dim3(16, 16, 4), 256, 0, stream>>>(qh, kh, Zbuf, out + (size_t)4194304);
  out_gemm<<<dim3(16, 32), 256, 0, stream>>>(ctx, Wob, b_out, out);
}

// Round 3
// 245.589 us; speedup vs baseline: 1.5411x; 1.0021x over previous
//
#include <hip/hip_runtime.h>

// MHA forward. L=S=1024, N=4, E=1024, H=16, hd=64, B=N*H=64, M=L*N=4096
// Inputs fp32, outputs fp32 (out0=attn_output 4.19M, out1=attn_weights 4.19M @+4194304).
// Round 9: round-8 qkv regressed (61.5us, MfmaUtil 15.7%) -- stage->drain->compute
// exposed full load latency per K-step (9.2k cy/step wall vs 400 cy compute).
// Fix: T3 minimum 2-phase: double-buffered BK=32 tiles (32KB LDS, keeps 3
// blocks/CU -- avoids the m132 64KB trap), STAGE(kt+1) issued right after the
// single per-step barrier, compute(kt) hides the load latency before the next
// vmcnt(0)+barrier. Swizzle re-derived for 64B rows: phys_chunk = logical ^
// ((row>>1)&3) -> 2-way bank alias (free) on ds_read_b128. Same for out_gemm.
// Attention + convert kernels unchanged; numerics identical.
typedef unsigned short u16;
typedef __attribute__((ext_vector_type(8))) short short8;   // 8 bf16 (4 VGPRs)
typedef __attribute__((ext_vector_type(4))) float f32x4;    // MFMA accumulator

__device__ __forceinline__ u16 f2bf(float f) {  // RNE
  unsigned int i = __float_as_uint(f);
  i += 0x7fffu + ((i >> 16) & 1u);
  return (u16)(i >> 16);
}

__device__ __forceinline__ short8 cvt8(const float* p) {
  float4 a = ((const float4*)p)[0];
  float4 b = ((const float4*)p)[1];
  short8 r;
  r[0] = (short)f2bf(a.x); r[1] = (short)f2bf(a.y);
  r[2] = (short)f2bf(a.z); r[3] = (short)f2bf(a.w);
  r[4] = (short)f2bf(b.x); r[5] = (short)f2bf(b.y);
  r[6] = (short)f2bf(b.z); r[7] = (short)f2bf(b.w);
  return r;
}

// ---------------------------------------------------------------------------
// Kernel 0: one-shot fp32 -> bf16 conversion of q/k/v/W_in/W_out. (unchanged)
// ---------------------------------------------------------------------------
__global__ __launch_bounds__(256) void convert_bf16(
    const float* __restrict__ q, const float* __restrict__ k,
    const float* __restrict__ v, const float* __restrict__ Wi,
    const float* __restrict__ Wo,
    u16* __restrict__ qb, u16* __restrict__ kb, u16* __restrict__ vb,
    u16* __restrict__ Wib, u16* __restrict__ Wob)
{
  const float* src; u16* dst; int len8;
  switch (blockIdx.y) {
    case 0:  src = q;  dst = qb;  len8 = 524288; break;  // 4M elts
    case 1:  src = k;  dst = kb;  len8 = 524288; break;
    case 2:  src = v;  dst = vb;  len8 = 524288; break;
    case 3:  src = Wi; dst = Wib; len8 = 393216; break;  // 3M elts
    default: src = Wo; dst = Wob; len8 = 131072; break;  // 1M elts
  }
  int stride = gridDim.x * 256;
  for (int i = blockIdx.x * 256 + threadIdx.x; i < len8; i += stride)
    *(short8*)(dst + (size_t)i * 8) = cvt8(src + (size_t)i * 8);
}

// ---------------------------------------------------------------------------
// Kernel 1: packed QKV projection. Round-9: 128x128 tile, BK=32, 2-phase
// double-buffer (one barrier/step, STAGE(kt+1) issued before compute(kt)).
// LDS 32KB -> 3 blocks/CU. Swizzle: 64B rows, 4x16B chunks, phys = log ^
// ((row>>1)&3); staged via pre-swizzled global source, linear LDS dest.
// C[m][j] = X[m][:].W[j][:] + bias[j]; M=4096, K=1024, J=3072 (bf16 inputs).
// ---------------------------------------------------------------------------
__global__ __launch_bounds__(256) void qkv_gemm(
    const u16* __restrict__ qb, const u16* __restrict__ kb,
    const u16* __restrict__ vb, const u16* __restrict__ W,
    const float* __restrict__ bias,
    u16* __restrict__ qh, u16* __restrict__ kh, u16* __restrict__ vt)
{
  __shared__ __align__(16) u16 As[2][128 * 32];   // 8 KB per buffer
  __shared__ __align__(16) u16 Bs[2][128 * 32];

  const int tid  = threadIdx.x;
  const int wave = tid >> 6;
  const int lane = tid & 63;
  const int r    = lane & 15;
  const int q4   = lane >> 4;
  const int wm   = wave >> 1;          // 0..1  (row quadrant)
  const int wn   = wave & 1;           // 0..1  (col quadrant)

  // XCD-chunked swizzle: one XCD covers 4 m-tiles x all j-tiles.
  const int orig = blockIdx.y * 24 + blockIdx.x;
  const int nid  = (orig & 7) * 96 + (orig >> 3);
  const int mt   = nid / 24;           // 0..31
  const int jt   = nid - mt * 24;      // 0..23
  const int src  = jt >> 3;            // 0=q, 1=k, 2=v
  const u16* X = (src == 0) ? qb : (src == 1) ? kb : vb;
  const int m0 = mt * 128;
  const int j0 = jt * 128;

  // staging: per gload_lds instr a wave covers 16 rows x 64B (1KB).
  // lane -> (row = lane>>2, phys chunk = lane&3); fetched logical chunk =
  // (lane&3) ^ ((lane>>3)&3)  [since (row>>1)&3 = (lane>>3)&3].
  const int lrow = lane >> 2;
  const int lchk = ((lane & 3) ^ ((lane >> 3) & 3)) << 4;   // byte offset
  const char* Xc = (const char*)X;
  const char* Wc = (const char*)W;

  // fragment-read: logical chunk q4 of row (..+r) lives at phys q4^((r>>1)&3)
  const int fchk = (q4 ^ ((r >> 1) & 3)) << 3;              // u16 offset

  f32x4 acc[4][4];
  #pragma unroll
  for (int a = 0; a < 4; ++a)
    #pragma unroll
    for (int b = 0; b < 4; ++b)
      acc[a][b] = (f32x4){0.f, 0.f, 0.f, 0.f};

  auto STAGE = [&](int buf, int kt) {
    const int kbyte = kt * 64;
    #pragma unroll
    for (int i = 0; i < 2; ++i) {
      const int g = wave * 2 + i;      // 16-row group 0..7
      __builtin_amdgcn_global_load_lds(
          (const u16*)(Xc + (size_t)(m0 + g * 16 + lrow) * 2048 + kbyte + lchk),
          &As[buf][g * 512], 16, 0, 0);
      __builtin_amdgcn_global_load_lds(
          (const u16*)(Wc + (size_t)(j0 + g * 16 + lrow) * 2048 + kbyte + lchk),
          &Bs[buf][g * 512], 16, 0, 0);
    }
  };

  STAGE(0, 0);
  for (int kt = 0; kt < 32; ++kt) {
    const int cur = kt & 1;
    __syncthreads();                   // vmcnt(0) drain: buf[cur] staged;
                                       // all waves done reading buf[cur^1]
    if (kt < 31) STAGE(cur ^ 1, kt + 1);

    short8 af[4], bf[4];
    #pragma unroll
    for (int mi = 0; mi < 4; ++mi)
      af[mi] = *(const short8*)(&As[cur][(wm * 64 + mi * 16 + r) * 32 + fchk]);
    #pragma unroll
    for (int ji = 0; ji < 4; ++ji)
      bf[ji] = *(const short8*)(&Bs[cur][(wn * 64 + ji * 16 + r) * 32 + fchk]);
    #pragma unroll
    for (int mi = 0; mi < 4; ++mi)
      #pragma unroll
      for (int ji = 0; ji < 4; ++ji)
        acc[mi][ji] = __builtin_amdgcn_mfma_f32_16x16x32_bf16(af[mi], bf[ji], acc[mi][ji], 0, 0, 0);
  }

  #pragma unroll
  for (int mi = 0; mi < 4; ++mi) {
    #pragma unroll
    for (int ji = 0; ji < 4; ++ji) {
      #pragma unroll
      for (int rr = 0; rr < 4; ++rr) {
        int m = m0 + wm * 64 + mi * 16 + q4 * 4 + rr;  // row = t*4+n
        int j = j0 + wn * 64 + ji * 16 + r;            // col in [0,3072)
        float v = acc[mi][ji][rr] + bias[j];
        int t = m >> 2, n = m & 3;
        int jj = j & 1023;
        int h = jj >> 6, d = jj & 63;
        int bb = n * 16 + h;
        if (src == 0)
          qh[(size_t)bb * 65536 + (size_t)t * 64 + d] = f2bf(v * 0.125f);
        else if (src == 1)
          kh[(size_t)bb * 65536 + (size_t)t * 64 + d] = f2bf(v);
        else
          vt[(size_t)bb * 65536 + (size_t)d * 1024 + t] = f2bf(v);   // transposed
      }
    }
  }
}

// ---------------------------------------------------------------------------
// Kernel 2: attention context, MFMA flash-style. (unchanged from round 7)
// ---------------------------------------------------------------------------
__global__ __launch_bounds__(256) void attn_ctx_mfma(
    const u16* __restrict__ qh, const u16* __restrict__ kh,
    const u16* __restrict__ vt, u16* __restrict__ ctx,
    float* __restrict__ Zbuf)
{
  __shared__ __align__(16) u16 Ks[2][4096];   // 64 rows x 8 chunks x 8 bf16
  __shared__ __align__(16) u16 Vs[2][4096];
  __shared__ __align__(16) u16 Pl[4][1024];   // per-wave P[16][64], swizzled

  const int tid = threadIdx.x;
  const int wv = tid >> 6, lane = tid & 63, r = lane & 15, q4 = lane >> 4;
  const int b  = blockIdx.y;
  const int lw = blockIdx.x * 64 + wv * 16;
  const int n = b >> 4, h = b & 15;

  const u16* qbase = qh + (size_t)b * 65536;
  const char* kc = (const char*)(kh + (size_t)b * 65536);
  const char* vc = (const char*)(vt + (size_t)b * 65536);
  u16* P = Pl[wv];

  const int ls  = lane >> 3;               // row-in-octet 0..7
  const int swzb = ((lane & 7) ^ ls) << 4; // swizzled 16B-chunk byte offset
  const int iw  = wv * 2;
  const size_t klo = (size_t)iw * 1024 + (size_t)ls * 128 + swzb;   // K row = 128 B
  const size_t vlo = (size_t)iw * 16384 + (size_t)ls * 2048 + swzb; // V row = 2048 B

  const int rsw = r & 7;
  const int c0 = (q4 ^ rsw) << 3;          // u16 offset of logical chunk q4
  const int c1 = ((q4 ^ rsw) ^ 4) << 3;    // logical chunk q4+4

  short8 aq0 = *(const short8*)(qbase + (size_t)(lw + r) * 64 + q4 * 8);
  short8 aq1 = *(const short8*)(qbase + (size_t)(lw + r) * 64 + 32 + q4 * 8);

  f32x4 oc[4];
  #pragma unroll
  for (int ji = 0; ji < 4; ++ji) oc[ji] = (f32x4){0.f, 0.f, 0.f, 0.f};
  float z[4] = {0.f, 0.f, 0.f, 0.f};

  {
    const char* kp = kc + klo;
    const char* vp = vc + vlo;
    u16* kd = &Ks[0][iw * 512];
    u16* vd = &Vs[0][iw * 512];
    __builtin_amdgcn_global_load_lds(kp,          kd,       16, 0, 0);
    __builtin_amdgcn_global_load_lds(kp + 1024,   kd + 512, 16, 0, 0);
    __builtin_amdgcn_global_load_lds(vp,          vd,       16, 0, 0);
    __builtin_amdgcn_global_load_lds(vp + 16384,  vd + 512, 16, 0, 0);
  }

  for (int it = 0; it < 16; ++it) {
    const int cur = it & 1;
    __syncthreads();   // drains vmcnt -> Ks/Vs[cur] staged; prev-iter reads done
    const u16* Kb = Ks[cur];
    const u16* Vb = Vs[cur];

    f32x4 sc[4];
    #pragma unroll
    for (int ji = 0; ji < 4; ++ji) {
      const int row = (ji * 16 + r) * 64;
      short8 bk0 = *(const short8*)(Kb + row + c0);
      short8 bk1 = *(const short8*)(Kb + row + c1);
      f32x4 t = (f32x4){0.f, 0.f, 0.f, 0.f};
      t = __builtin_amdgcn_mfma_f32_16x16x32_bf16(aq0, bk0, t, 0, 0, 0);
      t = __builtin_amdgcn_mfma_f32_16x16x32_bf16(aq1, bk1, t, 0, 0, 0);
      sc[ji] = t;
    }

    if (it < 15) {
      const char* kp = kc + (size_t)(it + 1) * 8192 + klo;  // 64 rows * 128 B
      const char* vp = vc + (size_t)(it + 1) * 128  + vlo;  // 64 cols * 2 B
      u16* kd = &Ks[cur ^ 1][iw * 512];
      u16* vd = &Vs[cur ^ 1][iw * 512];
      __builtin_amdgcn_global_load_lds(kp,          kd,       16, 0, 0);
      __builtin_amdgcn_global_load_lds(kp + 1024,   kd + 512, 16, 0, 0);
      __builtin_amdgcn_global_load_lds(vp,          vd,       16, 0, 0);
      __builtin_amdgcn_global_load_lds(vp + 16384,  vd + 512, 16, 0, 0);
    }

    #pragma unroll
    for (int ji = 0; ji < 4; ++ji) {
      const int cw = ji * 2 + (r >> 3);   // logical 8-elt chunk of col ji*16+r
      #pragma unroll
      for (int rr = 0; rr < 4; ++rr) {
        float e = __expf(sc[ji][rr]);
        z[rr] += e;
        const int row = q4 * 4 + rr;
        P[row * 64 + ((cw ^ (row & 7)) << 3) + (r & 7)] = f2bf(e);
      }
    }
    asm volatile("s_waitcnt lgkmcnt(0)" ::: "memory");
    short8 ap0 = *(const short8*)(P + r * 64 + c0);
    short8 ap1 = *(const short8*)(P + r * 64 + c1);
    #pragma unroll
    for (int ji = 0; ji < 4; ++ji) {
      const int row = (ji * 16 + r) * 64;
      short8 bv0 = *(const short8*)(Vb + row + c0);
      short8 bv1 = *(const short8*)(Vb + row + c1);
      oc[ji] = __builtin_amdgcn_mfma_f32_16x16x32_bf16(ap0, bv0, oc[ji], 0, 0, 0);
      oc[ji] = __builtin_amdgcn_mfma_f32_16x16x32_bf16(ap1, bv1, oc[ji], 0, 0, 0);
    }
  }

  #pragma unroll
  for (int rr = 0; rr < 4; ++rr) {
    float zz = z[rr];
    zz += __shfl_xor(zz, 1);
    zz += __shfl_xor(zz, 2);
    zz += __shfl_xor(zz, 4);
    zz += __shfl_xor(zz, 8);
    z[rr] = zz;
  }

  #pragma unroll
  for (int rr = 0; rr < 4; ++rr) {
    float inv = 1.0f / z[rr];
    int l = lw + q4 * 4 + rr;
    u16* crow = ctx + ((size_t)l * 4 + n) * 1024 + h * 64;
    #pragma unroll
    for (int ji = 0; ji < 4; ++ji)
      crow[ji * 16 + r] = f2bf(oc[ji][rr] * inv);
    if (r == 0) Zbuf[(size_t)b * 1024 + l] = z[rr];
  }
}

// ---------------------------------------------------------------------------
// Kernel 3: head-averaged attention weights. (unchanged from round 7)
// ---------------------------------------------------------------------------
__global__ __launch_bounds__(256) void attn_w_mfma(
    const u16* __restrict__ qh, const u16* __restrict__ kh,
    const float* __restrict__ Zbuf, float* __restrict__ out_w)
{
  __shared__ __align__(16) u16 Kw[2][4096];
  __shared__ float invZ[16][64];

  const int tid = threadIdx.x;
  const int wv = tid >> 6, lane = tid & 63, r = lane & 15, q4 = lane >> 4;
  const int lt = blockIdx.x;
  const int st = blockIdx.y;
  const int n  = blockIdx.z;
  const int l0 = lt * 64;
  const int s0 = st * 64;
  const int lw = l0 + wv * 16;

  const char* khc = (const char*)kh + (size_t)n * 2097152;  // 16 heads * 128 KB

  const int ls  = lane >> 3;
  const int swzb = ((lane & 7) ^ ls) << 4;
  const int iw  = wv * 2;
  const size_t klo = (size_t)s0 * 128 + (size_t)iw * 1024 + (size_t)ls * 128 + swzb;

  const int rsw = r & 7;
  const int c0 = (q4 ^ rsw) << 3;
  const int c1 = ((q4 ^ rsw) ^ 4) << 3;

  for (int i = tid; i < 1024; i += 256) {
    int hh = i >> 6, row = i & 63;
    invZ[hh][row] = 1.0f / (Zbuf[(size_t)(n * 16 + hh) * 1024 + l0 + row] * 16.0f);
  }

  {
    const char* kp = khc + klo;
    u16* kd = &Kw[0][iw * 512];
    __builtin_amdgcn_global_load_lds(kp,        kd,       16, 0, 0);
    __builtin_amdgcn_global_load_lds(kp + 1024, kd + 512, 16, 0, 0);
  }
  const u16* q0 = qh + (size_t)(n * 16) * 65536;
  short8 aqc0 = *(const short8*)(q0 + (size_t)(lw + r) * 64 + q4 * 8);
  short8 aqc1 = *(const short8*)(q0 + (size_t)(lw + r) * 64 + 32 + q4 * 8);

  f32x4 wacc[4];
  #pragma unroll
  for (int ji = 0; ji < 4; ++ji) wacc[ji] = (f32x4){0.f, 0.f, 0.f, 0.f};

  for (int hh = 0; hh < 16; ++hh) {
    const int cur = hh & 1;
    __syncthreads();   // Kw[cur] staged (and invZ on first iter); prev reads done
    if (hh < 15) {
      const char* kp = khc + (size_t)(hh + 1) * 131072 + klo;
      u16* kd = &Kw[cur ^ 1][iw * 512];
      __builtin_amdgcn_global_load_lds(kp,        kd,       16, 0, 0);
      __builtin_amdgcn_global_load_lds(kp + 1024, kd + 512, 16, 0, 0);
    }
    const int hn = (hh < 15) ? hh + 1 : hh;
    const u16* qn = qh + (size_t)(n * 16 + hn) * 65536;
    short8 an0 = *(const short8*)(qn + (size_t)(lw + r) * 64 + q4 * 8);
    short8 an1 = *(const short8*)(qn + (size_t)(lw + r) * 64 + 32 + q4 * 8);

    const u16* Kb = Kw[cur];
    f32x4 sc[4];
    #pragma unroll
    for (int ji = 0; ji < 4; ++ji) {
      const int row = (ji * 16 + r) * 64;
      short8 bk0 = *(const short8*)(Kb + row + c0);
      short8 bk1 = *(const short8*)(Kb + row + c1);
      f32x4 t = (f32x4){0.f, 0.f, 0.f, 0.f};
      t = __builtin_amdgcn_mfma_f32_16x16x32_bf16(aqc0, bk0, t, 0, 0, 0);
      t = __builtin_amdgcn_mfma_f32_16x16x32_bf16(aqc1, bk1, t, 0, 0, 0);
      sc[ji] = t;
    }
    #pragma unroll
    for (int rr = 0; rr < 4; ++rr) {
      float iv = invZ[hh][wv * 16 + q4 * 4 + rr];
      #pragma unroll
      for (int ji = 0; ji < 4; ++ji)
        wacc[ji][rr] += __expf(sc[ji][rr]) * iv;
    }
    aqc0 = an0; aqc1 = an1;
  }

  #pragma unroll
  for (int ji = 0; ji < 4; ++ji)
    #pragma unroll
    for (int rr = 0; rr < 4; ++rr) {
      int row = lw + q4 * 4 + rr;
      int col = s0 + ji * 16 + r;
      out_w[(size_t)n * 1048576 + (size_t)row * 1024 + col] = wacc[ji][rr];
    }
}

// ---------------------------------------------------------------------------
// Kernel 4: output projection. Round-9: 128(M)x64(J) tile, BK=32, 2-phase
// double-buffer (same recipe as qkv_gemm). LDS 24KB. Grid 512 (2/CU).
// ctx/Wob bf16 in, fp32 out. M=4096, K=1024, J=1024.
// ---------------------------------------------------------------------------
__global__ __launch_bounds__(256) void out_gemm(
    const u16* __restrict__ ctx, const u16* __restrict__ W,
    const float* __restrict__ bias, float* __restrict__ out)
{
  __shared__ __align__(16) u16 As[2][128 * 32];   // 8 KB per buffer
  __shared__ __align__(16) u16 Bs[2][64 * 32];    // 4 KB per buffer

  const int tid  = threadIdx.x;
  const int wave = tid >> 6;
  const int lane = tid & 63;
  const int r    = lane & 15;
  const int q4   = lane >> 4;
  const int wm   = wave >> 1;          // 0..1 (row half: 64 rows)
  const int wn   = wave & 1;           // 0..1 (col half: 32 cols)

  const int orig = blockIdx.y * 16 + blockIdx.x;
  const int nid  = (orig & 7) * 64 + (orig >> 3);
  const int mt   = nid >> 4;           // 0..31
  const int jt   = nid & 15;           // 0..15
  const int m0 = mt * 128;
  const int j0 = jt * 64;

  const int lrow = lane >> 2;
  const int lchk = ((lane & 3) ^ ((lane >> 3) & 3)) << 4;
  const char* Ac = (const char*)ctx;
  const char* Wc = (const char*)W;
  const int fchk = (q4 ^ ((r >> 1) & 3)) << 3;

  f32x4 acc[4][2];
  #pragma unroll
  for (int a = 0; a < 4; ++a)
    #pragma unroll
    for (int b = 0; b < 2; ++b)
      acc[a][b] = (f32x4){0.f, 0.f, 0.f, 0.f};

  auto STAGE = [&](int buf, int kt) {
    const int kbyte = kt * 64;
    #pragma unroll
    for (int i = 0; i < 2; ++i) {
      const int g = wave * 2 + i;      // A group 0..7
      __builtin_amdgcn_global_load_lds(
          (const u16*)(Ac + (size_t)(m0 + g * 16 + lrow) * 2048 + kbyte + lchk),
          &As[buf][g * 512], 16, 0, 0);
    }
    __builtin_amdgcn_global_load_lds(
        (const u16*)(Wc + (size_t)(j0 + wave * 16 + lrow) * 2048 + kbyte + lchk),
        &Bs[buf][wave * 512], 16, 0, 0);
  };

  STAGE(0, 0);
  for (int kt = 0; kt < 32; ++kt) {
    const int cur = kt & 1;
    __syncthreads();
    if (kt < 31) STAGE(cur ^ 1, kt + 1);

    short8 af[4], bf[2];
    #pragma unroll
    for (int mi = 0; mi < 4; ++mi)
      af[mi] = *(const short8*)(&As[cur][(wm * 64 + mi * 16 + r) * 32 + fchk]);
    #pragma unroll
    for (int ji = 0; ji < 2; ++ji)
      bf[ji] = *(const short8*)(&Bs[cur][(wn * 32 + ji * 16 + r) * 32 + fchk]);
    #pragma unroll
    for (int mi = 0; mi < 4; ++mi)
      #pragma unroll
      for (int ji = 0; ji < 2; ++ji)
        acc[mi][ji] = __builtin_amdgcn_mfma_f32_16x16x32_bf16(af[mi], bf[ji], acc[mi][ji], 0, 0, 0);
  }

  #pragma unroll
  for (int mi = 0; mi < 4; ++mi) {
    #pragma unroll
    for (int ji = 0; ji < 2; ++ji) {
      #pragma unroll
      for (int rr = 0; rr < 4; ++rr) {
        int m = m0 + wm * 64 + mi * 16 + q4 * 4 + rr;
        int j = j0 + wn * 32 + ji * 16 + r;
        out[(size_t)m * 1024 + j] = acc[mi][ji][rr] + bias[j];
      }
    }
  }
}

// ---------------------------------------------------------------------------
extern "C" void kernel_launch(void* const* d_in, const int* in_sizes, int n_in,
                              void* d_out, int out_size, void* d_ws, size_t ws_size,
                              hipStream_t stream) {
  const float* query = (const float*)d_in[0];
  const float* key   = (const float*)d_in[1];
  const float* value = (const float*)d_in[2];
  const float* W_in  = (const float*)d_in[3];
  const float* b_in  = (const float*)d_in[4];
  const float* W_out = (const float*)d_in[5];
  const float* b_out = (const float*)d_in[6];
  float* out = (float*)d_out;

  // ws (~64.3 MB): qb 8 | kb 8 | vb 8 | Wib 6 | Wob 2 | qh 8 | kh 8 | vt 8 | ctx 8 | Z .25
  u16* qb  = (u16*)d_ws;
  u16* kb  = qb  + (size_t)4194304;
  u16* vb  = kb  + (size_t)4194304;
  u16* Wib = vb  + (size_t)4194304;
  u16* Wob = Wib + (size_t)3145728;
  u16* qh  = Wob + (size_t)1048576;
  u16* kh  = qh  + (size_t)4194304;
  u16* vt  = kh  + (size_t)4194304;
  u16* ctx = vt  + (size_t)4194304;
  float* Zbuf = (float*)(ctx + (size_t)4194304);

  convert_bf16<<<dim3(512, 5), 256, 0, stream>>>(query, key, value, W_in, W_out,
                                                 qb, kb, vb, Wib, Wob);
  qkv_gemm<<<dim3(24, 32), 256, 0, stream>>>(qb, kb, vb, Wib, b_in, qh, kh, vt);
  attn_ctx_mfma<<<dim3(16, 64), 256, 0, stream>>>(qh, kh, vt, ctx, Zbuf);
  attn_w_mfma<<<dim3(16, 16, 4), 256, 0, stream>>>(qh, kh, Zbuf, out + (size_t)4194304);
  out_gemm<<<dim3(16, 32), 256, 0, stream>>>(ctx, Wob, b_out, out);
}